// Round 16
// baseline (300.274 us; speedup 1.0000x reference)
//
#include <hip/hip_runtime.h>

// ---- problem constants ----
#define SRAD 3
#define TRAD 1
#define Hdim 256
#define Wdim 256
#define Tdim 32
#define CS (Hdim*Wdim*Tdim)

// ---- tiling: 8x8x8 tile, 2 t-adjacent outputs/thread, 2 blocks/CU ----
#define TH 8
#define TW 8
#define TT 8
#define HS (TH + 2*SRAD)      // 14
#define WS (TW + 2*SRAD)      // 14
#define TSZ (TT + 2*TRAD)     // 10 real t-px per row
#define RS 11                 // odd row stride -> uniform b128 bank residues for pair layout
#define NROWS (HS*WS)         // 196
#define NPX (NROWS*TSZ)       // 1960 real px
#define NSLOT (NROWS*RS)      // 2156 padded slots
#define NTHREADS 1024
#define NSUB 4
#define NPAIR 256             // t-pairs per tile (8*8*4)

// LDS planes (dword offsets), per px slot (9 dwords = 36 B):
//   AG [NSLOT][4] : (g0,g1)(g2,g3)(g4,g5)(g6,g7)  fp16 pairs, sqrt(sigma*log2e)-scaled
//   EVN[NSLOT][4] : (e0',e1')(v0,v1)(e2',v2)(n0,n1) fp16 pairs, e' = e/gamma
//   X  [NSLOT][1] : (g8,n2) fp16 pair
#define EVN_OFF (4*NSLOT)
#define X_OFF   (8*NSLOT)
#define SMEM_BYTES (9*NSLOT*4)   // 77,616 B -> 2 blocks/CU with VGPR <= 32

// skip: weights below 2^-16 are invisible (den >= 1 always, center weight == 1 exactly)
#define SKIP_DIST 16.0f

typedef _Float16 half2_t __attribute__((ext_vector_type(2)));

#if defined(__has_builtin)
#if __has_builtin(__builtin_amdgcn_fdot2)
#define HAVE_FDOT2 1
#else
#define HAVE_FDOT2 0
#endif
#if __has_builtin(__builtin_amdgcn_exp2f)
#define EXPW(x) __builtin_amdgcn_exp2f(x)
#define LOG2E_SC 1.4426950408889634f
#else
#define EXPW(x) __expf(x)
#define LOG2E_SC 1.0f
#endif
#if __has_builtin(__builtin_elementwise_fma)
#define PKFMA(a, b, c) __builtin_elementwise_fma((a), (b), (c))
#else
#define PKFMA(a, b, c) ((a) * (b) + (c))
#endif
#if __has_builtin(__builtin_fminf16)
#define HMIN(a, b) __builtin_fminf16((a), (b))
#else
#define HMIN(a, b) ((a) < (b) ? (a) : (b))
#endif
#else
#define HAVE_FDOT2 0
#define EXPW(x) __expf(x)
#define LOG2E_SC 1.0f
#define PKFMA(a, b, c) ((a) * (b) + (c))
#define HMIN(a, b) ((a) < (b) ? (a) : (b))
#endif

#define INVG 0.343100187f   // 1 / 2.9146

static __device__ __forceinline__ unsigned pack_h2(float a, float b) {
    return __builtin_bit_cast(unsigned, __builtin_amdgcn_cvt_pkrtz(a, b));
}
static __device__ __forceinline__ half2_t h2(unsigned u) {
    return __builtin_bit_cast(half2_t, u);
}
static __device__ __forceinline__ float fd2(half2_t d, float acc) {
#if HAVE_FDOT2
    return __builtin_amdgcn_fdot2(d, d, acc, false);
#else
    float a = (float)d.x, b = (float)d.y;
    return __builtin_fmaf(a, a, __builtin_fmaf(b, b, acc));
#endif
}
// full 9-channel squared distance (f16 diffs, f32 accumulate, 2 chains for ILP)
static __device__ __forceinline__ float distf(uint4 a, unsigned xv, uint4 A, _Float16 g8) {
    float da = 0.f, db = 0.f;
    half2_t d;
    d = h2(a.x) - h2(A.x); da = fd2(d, da);
    d = h2(a.y) - h2(A.y); db = fd2(d, db);
    d = h2(a.z) - h2(A.z); da = fd2(d, da);
    d = h2(a.w) - h2(A.w); db = fd2(d, db);
    const _Float16 d8 = h2(xv).x - g8;
    const float dl = (float)d8;
    da = __builtin_fmaf(dl, dl, da);
    return da + db;
}

__global__ __launch_bounds__(NTHREADS, 8) void statden_kernel(
    const float* __restrict__ noisy, const float* __restrict__ guidance,
    const float* __restrict__ est, const float* __restrict__ var,
    const float* __restrict__ sigma_inv, float* __restrict__ out)
{
    extern __shared__ unsigned char smem[];
    unsigned* agP  = (unsigned*)smem;
    unsigned* evnP = agP + EVN_OFF;
    unsigned* xP   = agP + X_OFF;

    const int tid = threadIdx.x;
    const int pp  = tid & (NPAIR - 1);
    const int sub = tid >> 8;            // 4-way offset split (4-wave-uniform)
    const int h0 = blockIdx.y * TH;
    const int w0 = blockIdx.x * TW;
    const int t0 = blockIdx.z * TT;

    float sq[9];
    #pragma unroll
    for (int c = 0; c < 9; ++c) sq[c] = sqrtf(sigma_inv[c] * LOG2E_SC);

    // ---- stage halo (zero-fill OOB == reference zero padding) ----
    for (int p = tid; p < NPX; p += NTHREADS) {
        int row = p / TSZ;
        int t   = p - row * TSZ;
        int pw  = row % WS;
        int ph  = row / WS;
        int h = h0 - SRAD + ph;
        int w = w0 - SRAD + pw;
        int tg = t0 - TRAD + t;
        bool ok = ((unsigned)h < (unsigned)Hdim) && ((unsigned)w < (unsigned)Wdim)
               && ((unsigned)tg < (unsigned)Tdim);
        int base = (h * Wdim + w) * Tdim + tg;

        float g[9];
        #pragma unroll
        for (int c = 0; c < 9; ++c) g[c] = ok ? guidance[c*CS + base] * sq[c] : 0.f;
        float e0 = ok ? est[0*CS + base] * INVG : 0.f;
        float e1 = ok ? est[1*CS + base] * INVG : 0.f;
        float e2 = ok ? est[2*CS + base] * INVG : 0.f;
        float v0 = ok ? var[0*CS + base] : 0.f;
        float v1 = ok ? var[1*CS + base] : 0.f;
        float v2 = ok ? var[2*CS + base] : 0.f;
        float n0 = ok ? noisy[0*CS + base] : 0.f;
        float n1 = ok ? noisy[1*CS + base] : 0.f;
        float n2 = ok ? noisy[2*CS + base] : 0.f;

        const int idx = row * RS + t;
        uint4 ag;
        ag.x = pack_h2(g[0], g[1]); ag.y = pack_h2(g[2], g[3]);
        ag.z = pack_h2(g[4], g[5]); ag.w = pack_h2(g[6], g[7]);
        *(uint4*)(agP + 4*idx) = ag;
        uint4 ev;
        ev.x = pack_h2(e0, e1); ev.y = pack_h2(v0, v1);
        ev.z = pack_h2(e2, v2); ev.w = pack_h2(n0, n1);
        *(uint4*)(evnP + 4*idx) = ev;
        xP[idx] = pack_h2(g[8], n2);
    }
    __syncthreads();

    // ---- per-thread t-pair: outputs at t0+2*tt2, t0+2*tt2+1 ----
    const int tt2 = pp & 3;
    const int ww  = (pp >> 2) & 7;
    const int hh  = pp >> 5;
    const int crow = (hh + SRAD) * WS + (ww + SRAD);
    const int cidx = crow * RS + 2 * tt2;   // window slot k=0 (dt=-1 of output 0)
    const int ci0 = cidx + 1;               // center of output 0
    const int ci1 = cidx + 2;               // center of output 1

    // center guidance only (EVN center is re-read from LDS in the rare pass path)
    const uint4 A0 = *(const uint4*)(agP + 4*ci0);
    const uint4 A1 = *(const uint4*)(agP + 4*ci1);
    const _Float16 g80 = h2(xP[ci0]).x;
    const _Float16 g81 = h2(xP[ci1]).x;

    float nm0[2] = {0.f, 0.f}, nm1[2] = {0.f, 0.f}, nm2[2] = {0.f, 0.f};
    float den[2] = {0.f, 0.f};

// pass-path accumulate for output J against neighbor slot NI (center EVN re-read)
#define ACCUM(NI, XV, DIST, J, CIJ) do {                                 \
    const uint4 e  = *(const uint4*)(evnP + 4*(NI));                     \
    const uint4 ex = *(const uint4*)(evnP + 4*(CIJ));                    \
    const float wjf = EXPW(-(DIST));                                     \
    const half2_t de01 = h2(e.x) - h2(ex.x);                             \
    const half2_t vs01 = h2(e.y) + h2(ex.y);                             \
    const half2_t m01  = PKFMA(-de01, de01, vs01);                       \
    const half2_t s2   = h2(e.z) + h2(ex.z ^ 0x00008000u);               \
    const _Float16 m2v = __builtin_fmaf16(-s2.x, s2.x, s2.y);            \
    const _Float16 mn  = HMIN(HMIN(m01.x, m01.y), m2v);                  \
    const float wgt = (mn >= (_Float16)0) ? wjf : 0.f;                   \
    nm0[J] = __builtin_fmaf(wgt, (float)h2(e.w).x, nm0[J]);              \
    nm1[J] = __builtin_fmaf(wgt, (float)h2(e.w).y, nm1[J]);              \
    nm2[J] = __builtin_fmaf(wgt, (float)h2(XV).y,  nm2[J]);              \
    den[J] += wgt;                                                       \
} while (0)

    #pragma unroll 1
    for (int it = sub; it < 49; it += NSUB) {
        const int dhp = it / 7;
        const int dwp = it - dhp * 7;
        const int nbase = cidx + ((dhp - SRAD) * WS + (dwp - SRAD)) * RS;

        // slot k=0: output 0 only (dt=-1)
        {
            const int ni = nbase;
            const uint4 a = *(const uint4*)(agP + 4*ni);
            const unsigned xv = xP[ni];
            const float d0 = distf(a, xv, A0, g80);
            if (__ballot(d0 <= SKIP_DIST)) { ACCUM(ni, xv, d0, 0, ci0); }
        }
        // slot k=1: both outputs
        {
            const int ni = nbase + 1;
            const uint4 a = *(const uint4*)(agP + 4*ni);
            const unsigned xv = xP[ni];
            const float d0 = distf(a, xv, A0, g80);
            const float d1 = distf(a, xv, A1, g81);
            if (__ballot(fminf(d0, d1) <= SKIP_DIST)) {
                ACCUM(ni, xv, d0, 0, ci0);
                ACCUM(ni, xv, d1, 1, ci1);
            }
        }
        // slot k=2: both outputs
        {
            const int ni = nbase + 2;
            const uint4 a = *(const uint4*)(agP + 4*ni);
            const unsigned xv = xP[ni];
            const float d0 = distf(a, xv, A0, g80);
            const float d1 = distf(a, xv, A1, g81);
            if (__ballot(fminf(d0, d1) <= SKIP_DIST)) {
                ACCUM(ni, xv, d0, 0, ci0);
                ACCUM(ni, xv, d1, 1, ci1);
            }
        }
        // slot k=3: output 1 only (dt=+1)
        {
            const int ni = nbase + 3;
            const uint4 a = *(const uint4*)(agP + 4*ni);
            const unsigned xv = xP[ni];
            const float d1 = distf(a, xv, A1, g81);
            if (__ballot(d1 <= SKIP_DIST)) { ACCUM(ni, xv, d1, 1, ci1); }
        }
    }

    // ---- combine 4 offset-split partials via LDS ----
    __syncthreads();
    float* red = (float*)smem;   // 3 * 256 * 8 * 4 B = 24,576 B, reuse staged region
    const int sw = (pp & 1) << 2;           // swizzle: spread the two float4s
    if (sub != 0) {
        const int base = ((sub - 1) * NPAIR + pp) * 8;
        float4 v0; v0.x = nm0[0]; v0.y = nm1[0]; v0.z = nm2[0]; v0.w = den[0];
        float4 v1; v1.x = nm0[1]; v1.y = nm1[1]; v1.z = nm2[1]; v1.w = den[1];
        *(float4*)(red + base + sw)       = v0;
        *(float4*)(red + base + (sw ^ 4)) = v1;
    }
    __syncthreads();
    if (sub == 0) {
        #pragma unroll
        for (int s = 0; s < NSUB - 1; ++s) {
            const int base = (s * NPAIR + pp) * 8;
            float4 v0 = *(const float4*)(red + base + sw);
            float4 v1 = *(const float4*)(red + base + (sw ^ 4));
            nm0[0] += v0.x; nm1[0] += v0.y; nm2[0] += v0.z; den[0] += v0.w;
            nm0[1] += v1.x; nm1[1] += v1.y; nm2[1] += v1.z; den[1] += v1.w;
        }
        const float inv0 = 1.0f / (den[0] + 1e-10f);
        const float inv1 = 1.0f / (den[1] + 1e-10f);

        const int hG = h0 + hh, wG = w0 + ww;
        const int ob = (hG * Wdim + wG) * Tdim + t0 + 2 * tt2;
        float2 o;
        o.x = nm0[0] * inv0; o.y = nm0[1] * inv1; *(float2*)(out + 0*CS + ob) = o;
        o.x = nm1[0] * inv0; o.y = nm1[1] * inv1; *(float2*)(out + 1*CS + ob) = o;
        o.x = nm2[0] * inv0; o.y = nm2[1] * inv1; *(float2*)(out + 2*CS + ob) = o;
    }
}

extern "C" void kernel_launch(void* const* d_in, const int* in_sizes, int n_in,
                              void* d_out, int out_size, void* d_ws, size_t ws_size,
                              hipStream_t stream) {
    const float* noisy    = (const float*)d_in[0];
    const float* guidance = (const float*)d_in[1];
    const float* est      = (const float*)d_in[2];
    const float* var      = (const float*)d_in[3];
    const float* sig      = (const float*)d_in[4];
    float* out = (float*)d_out;

    (void)in_sizes; (void)n_in; (void)out_size; (void)d_ws; (void)ws_size;

    (void)hipFuncSetAttribute(reinterpret_cast<const void*>(statden_kernel),
                              hipFuncAttributeMaxDynamicSharedMemorySize, SMEM_BYTES);

    dim3 grid(Wdim / TW, Hdim / TH, Tdim / TT);   // (32, 32, 4)
    statden_kernel<<<grid, NTHREADS, SMEM_BYTES, stream>>>(noisy, guidance, est, var, sig, out);
}

// Round 17
// 283.466 us; speedup vs baseline: 1.0593x; 1.0593x over previous
//
#include <hip/hip_runtime.h>

// ---- problem constants ----
#define SRAD 3
#define TRAD 1
#define Hdim 256
#define Wdim 256
#define Tdim 32
#define CS (Hdim*Wdim*Tdim)

// ---- tiling: 8x8x8 tile, 1 output/thread, 2 blocks/CU ----
#define TH 8
#define TW 8
#define TT 8
#define HS (TH + 2*SRAD)      // 14
#define WS (TW + 2*SRAD)      // 14
#define TSZ (TT + 2*TRAD)     // 10 real t-px per row
#define RS 10                 // == TSZ: bank-uniform for 1-output lane layout (tt spans 0..7)
#define NROWS (HS*WS)         // 196
#define NPX (NROWS*TSZ)       // 1960
#define NSLOT NPX             // 1960 (no pad slots)
#define NTHREADS 1024
#define NSUB 2
#define NCOL 512              // output px per tile

// LDS planes (dword offsets), per px slot (10 dwords = 40 B):
//   AG [NSLOT][4] : (g0,g1)(g2,g3)(g4,g5)(g6,g7)  fp16 pairs, sqrt(sigma*log2e)-scaled
//   EVN[NSLOT][4] : (e0',e1')(v0,v1)(e2',v2)(n0,n1) fp16 pairs, e' = e/gamma
//   X2 [NSLOT][2] : (g8,n2) fp16 pair | S f32 (S = scaled-g self-dot, eval-chain order)
#define EVN_OFF (4*NSLOT)
#define X2_OFF  (8*NSLOT)
#define SMEM_BYTES (10*NSLOT*4)  // 78,400 B -> 2 blocks/CU

// skip threshold: den >= 1 always (center weight == 1 exactly), dropped weights
// <= 2^-16 each -> output perturbation <= 146 * 2^-16 * |n|max ~ 0.012 worst-case
#define SKIP_ND (-16.0f)

typedef _Float16 half2_t __attribute__((ext_vector_type(2)));

#if defined(__has_builtin)
#if __has_builtin(__builtin_amdgcn_fdot2)
#define HAVE_FDOT2 1
#else
#define HAVE_FDOT2 0
#endif
#if __has_builtin(__builtin_amdgcn_exp2f)
#define EXPW(x) __builtin_amdgcn_exp2f(x)
#define LOG2E_SC 1.4426950408889634f
#else
#define EXPW(x) __expf(x)
#define LOG2E_SC 1.0f
#endif
#if __has_builtin(__builtin_elementwise_fma)
#define PKFMA(a, b, c) __builtin_elementwise_fma((a), (b), (c))
#else
#define PKFMA(a, b, c) ((a) * (b) + (c))
#endif
#if __has_builtin(__builtin_fminf16)
#define HMIN(a, b) __builtin_fminf16((a), (b))
#else
#define HMIN(a, b) ((a) < (b) ? (a) : (b))
#endif
#else
#define HAVE_FDOT2 0
#define EXPW(x) __expf(x)
#define LOG2E_SC 1.0f
#define PKFMA(a, b, c) ((a) * (b) + (c))
#define HMIN(a, b) ((a) < (b) ? (a) : (b))
#endif

#define INVG 0.343100187f   // 1 / 2.9146

static __device__ __forceinline__ unsigned pack_h2(float a, float b) {
    return __builtin_bit_cast(unsigned, __builtin_amdgcn_cvt_pkrtz(a, b));
}
static __device__ __forceinline__ half2_t h2(unsigned u) {
    return __builtin_bit_cast(half2_t, u);
}
// acc += y . x over the 2 fp16 lanes (v_dot2_f32_f16)
static __device__ __forceinline__ float dot2p(unsigned y, half2_t x, float acc) {
#if HAVE_FDOT2
    return __builtin_amdgcn_fdot2(h2(y), x, acc, false);
#else
    half2_t yv = h2(y);
    acc = __builtin_fmaf((float)yv.x, (float)x.x, acc);
    acc = __builtin_fmaf((float)yv.y, (float)x.y, acc);
    return acc;
#endif
}
static __device__ __forceinline__ float dot2s(unsigned y, unsigned x, float acc) {
    return dot2p(y, h2(x), acc);
}

__global__ __launch_bounds__(NTHREADS, 8) void statden_kernel(
    const float* __restrict__ noisy, const float* __restrict__ guidance,
    const float* __restrict__ est, const float* __restrict__ var,
    const float* __restrict__ sigma_inv, float* __restrict__ out)
{
    extern __shared__ unsigned char smem[];
    unsigned* agP  = (unsigned*)smem;
    unsigned* evnP = agP + EVN_OFF;
    unsigned* x2P  = agP + X2_OFF;

    const int tid = threadIdx.x;
    const int pix = tid & (NCOL - 1);
    const int sub = tid >> 9;            // 2-way checkerboard split (8-wave-uniform)
    const int h0 = blockIdx.y * TH;
    const int w0 = blockIdx.x * TW;
    const int t0 = blockIdx.z * TT;

    float sq[9];
    #pragma unroll
    for (int c = 0; c < 9; ++c) sq[c] = sqrtf(sigma_inv[c] * LOG2E_SC);

    // ---- stage halo (zero-fill OOB == reference zero padding) ----
    for (int p = tid; p < NPX; p += NTHREADS) {
        int row = p / TSZ;
        int t   = p - row * TSZ;
        int pw  = row % WS;
        int ph  = row / WS;
        int h = h0 - SRAD + ph;
        int w = w0 - SRAD + pw;
        int tg = t0 - TRAD + t;
        bool ok = ((unsigned)h < (unsigned)Hdim) && ((unsigned)w < (unsigned)Wdim)
               && ((unsigned)tg < (unsigned)Tdim);
        int base = (h * Wdim + w) * Tdim + tg;

        float g[9];
        #pragma unroll
        for (int c = 0; c < 9; ++c) g[c] = ok ? guidance[c*CS + base] * sq[c] : 0.f;
        float e0 = ok ? est[0*CS + base] * INVG : 0.f;
        float e1 = ok ? est[1*CS + base] * INVG : 0.f;
        float e2 = ok ? est[2*CS + base] * INVG : 0.f;
        float v0 = ok ? var[0*CS + base] : 0.f;
        float v1 = ok ? var[1*CS + base] : 0.f;
        float v2 = ok ? var[2*CS + base] : 0.f;
        float n0 = ok ? noisy[0*CS + base] : 0.f;
        float n1 = ok ? noisy[1*CS + base] : 0.f;
        float n2 = ok ? noisy[2*CS + base] : 0.f;

        // slot index == linear p (RS == TSZ, no padding)
        uint4 ag;
        ag.x = pack_h2(g[0], g[1]); ag.y = pack_h2(g[2], g[3]);
        ag.z = pack_h2(g[4], g[5]); ag.w = pack_h2(g[6], g[7]);
        *(uint4*)(agP + 4*p) = ag;
        uint4 ev;
        ev.x = pack_h2(e0, e1); ev.y = pack_h2(v0, v1);
        ev.z = pack_h2(e2, v2); ev.w = pack_h2(n0, n1);
        *(uint4*)(evnP + 4*p) = ev;
        unsigned xq = pack_h2(g[8], n2);
        // S from PACKED values, identical chain order as eval dot -> center dist == 0
        half2_t x8 = h2(xq);
        float S = __builtin_fmaf((float)x8.x, (float)x8.x, 0.f);
        S = dot2s(ag.x, ag.x, S);
        S = dot2s(ag.y, ag.y, S);
        S = dot2s(ag.z, ag.z, S);
        S = dot2s(ag.w, ag.w, S);
        uint2 x2; x2.x = xq; x2.y = __builtin_bit_cast(unsigned, S);
        *(uint2*)(x2P + 2*p) = x2;
    }
    __syncthreads();

    // ---- per-thread single output px ----
    const int tt = pix & 7;
    const int ww = (pix >> 3) & 7;
    const int hh = pix >> 6;
    const int crow = (hh + SRAD) * WS + (ww + SRAD);
    const int cidx = crow * RS + tt;    // window slot for tp=0 (dt=-1)
    const int ci = cidx + 1;            // center slot

    // center guidance terms only (center EVN re-read from LDS in rare pass path)
    half2_t agx0, agx1, agx2, agx3;
    float cgxf, Sx;
    {
        uint4 cag = *(const uint4*)(agP + 4*ci);
        agx0 = h2(cag.x); agx1 = h2(cag.y);
        agx2 = h2(cag.z); agx3 = h2(cag.w);
        uint2 cx2 = *(const uint2*)(x2P + 2*ci);
        cgxf = (float)h2(cx2.x).x;
        Sx   = __builtin_bit_cast(float, cx2.y);
    }

    float nm0 = 0.f, nm1 = 0.f, nm2 = 0.f, den = 0.f;

// dot-form negative distance for slot data (A = uint4 AG, X = uint2 X2)
#define NDIST(A, X, ND) do {                                             \
    float dot = __builtin_fmaf((float)h2(X.x).x, cgxf, 0.f);             \
    dot = dot2p(A.x, agx0, dot);                                         \
    dot = dot2p(A.y, agx1, dot);                                         \
    dot = dot2p(A.z, agx2, dot);                                         \
    dot = dot2p(A.w, agx3, dot);                                         \
    const float ssum = __builtin_bit_cast(float, X.y) + Sx;              \
    ND = __builtin_fmaf(2.0f, dot, -ssum);                               \
} while (0)

// pass path for one slot: t-test + accumulate (center EVN re-read from LDS)
#define PASS(NI, X, ND) do {                                             \
    const uint4 e  = *(const uint4*)(evnP + 4*(NI));                     \
    const uint4 ex = *(const uint4*)(evnP + 4*ci);                       \
    const float wjf = EXPW(ND);                                          \
    const half2_t de01 = h2(e.x) - h2(ex.x);                             \
    const half2_t vs01 = h2(e.y) + h2(ex.y);                             \
    const half2_t m01  = PKFMA(-de01, de01, vs01);                       \
    const half2_t s2   = h2(e.z) + h2(ex.z ^ 0x00008000u);               \
    const _Float16 m2v = __builtin_fmaf16(-s2.x, s2.x, s2.y);            \
    const _Float16 mn  = HMIN(HMIN(m01.x, m01.y), m2v);                  \
    const float wgt = (mn >= (_Float16)0) ? wjf : 0.f;                   \
    nm0 = __builtin_fmaf(wgt, (float)h2(e.w).x, nm0);                    \
    nm1 = __builtin_fmaf(wgt, (float)h2(e.w).y, nm1);                    \
    nm2 = __builtin_fmaf(wgt, (float)h2(X.x).y,  nm2);                   \
    den += wgt;                                                          \
} while (0)

    #pragma unroll 1
    for (int dh = 0; dh < 7; ++dh) {
        #pragma unroll 1
        for (int dw = ((dh + sub) & 1); dw < 7; dw += 2) {
            const int nbase = cidx + ((dh - SRAD) * WS + (dw - SRAD)) * RS;

            // branchless always-path: 6 loads + 3 independent dist chains
            const uint4 a0 = *(const uint4*)(agP + 4*nbase);
            const uint4 a1 = *(const uint4*)(agP + 4*(nbase + 1));
            const uint4 a2 = *(const uint4*)(agP + 4*(nbase + 2));
            const uint2 q0 = *(const uint2*)(x2P + 2*nbase);
            const uint2 q1 = *(const uint2*)(x2P + 2*(nbase + 1));
            const uint2 q2 = *(const uint2*)(x2P + 2*(nbase + 2));
            float nd0, nd1, nd2;
            NDIST(a0, q0, nd0);
            NDIST(a1, q1, nd1);
            NDIST(a2, q2, nd2);

            // one combined vote per 3 slots
            const float ndmax = fmaxf(nd0, fmaxf(nd1, nd2));
            if (__ballot(ndmax >= SKIP_ND)) {
                PASS(nbase,     q0, nd0);
                PASS(nbase + 1, q1, nd1);
                PASS(nbase + 2, q2, nd2);
            }
        }
    }

    // ---- combine 2 checkerboard partials via LDS ----
    __syncthreads();
    float* red = (float*)smem;   // 512 * 4 * 4 B = 8 KB, reuse staged region
    if (sub == 1) {
        float4 v; v.x = nm0; v.y = nm1; v.z = nm2; v.w = den;
        *(float4*)(red + 4 * pix) = v;
    }
    __syncthreads();
    if (sub == 0) {
        float4 v = *(const float4*)(red + 4 * pix);
        nm0 += v.x; nm1 += v.y; nm2 += v.z; den += v.w;
        const float inv = 1.0f / (den + 1e-10f);

        const int hG = h0 + hh, wG = w0 + ww;
        const int ob = (hG * Wdim + wG) * Tdim + t0 + tt;
        out[0*CS + ob] = nm0 * inv;
        out[1*CS + ob] = nm1 * inv;
        out[2*CS + ob] = nm2 * inv;
    }
}

extern "C" void kernel_launch(void* const* d_in, const int* in_sizes, int n_in,
                              void* d_out, int out_size, void* d_ws, size_t ws_size,
                              hipStream_t stream) {
    const float* noisy    = (const float*)d_in[0];
    const float* guidance = (const float*)d_in[1];
    const float* est      = (const float*)d_in[2];
    const float* var      = (const float*)d_in[3];
    const float* sig      = (const float*)d_in[4];
    float* out = (float*)d_out;

    (void)in_sizes; (void)n_in; (void)out_size; (void)d_ws; (void)ws_size;

    (void)hipFuncSetAttribute(reinterpret_cast<const void*>(statden_kernel),
                              hipFuncAttributeMaxDynamicSharedMemorySize, SMEM_BYTES);

    dim3 grid(Wdim / TW, Hdim / TH, Tdim / TT);   // (32, 32, 4)
    statden_kernel<<<grid, NTHREADS, SMEM_BYTES, stream>>>(noisy, guidance, est, var, sig, out);
}